// Round 1
// baseline (256.675 us; speedup 1.0000x reference)
//
#include <hip/hip_runtime.h>

// dist[N,K] = ||feat_n||^2 + ||cent_k||^2 - 2 feat . cent
// N=16384, K=2048, D=1024, fp32 in/out.
// bf16 MFMA GEMM, 256x256 tile, BK=64, 8 waves (2Mx4N), 128 KiB double-buffered
// LDS, 8-phase schedule with counted vmcnt(8) (never drained mid-loop),
// setprio(1) around MFMA clusters, 16B-chunk XOR bank swizzle, XCD-aware remap.
// Prep: one wave per row, bf16 convert + exact fp32 norms.

#define MROWS 16384
#define NCOLS 2048
#define DDIM  1024
#define BM 256
#define BN 256
#define BK 64
#define NTILES (DDIM / BK)   // 16

typedef unsigned short u16;
typedef unsigned int   u32;
typedef __attribute__((ext_vector_type(8))) short          short8;
typedef __attribute__((ext_vector_type(8))) unsigned short ushort8;
typedef __attribute__((ext_vector_type(4))) float          float4v;

__device__ __forceinline__ u16 f32_to_bf16_rne(float f) {
  u32 u = __float_as_uint(f);
  u32 r = u + 0x7FFFu + ((u >> 16) & 1u);   // round-to-nearest-even
  return (u16)(r >> 16);
}

// One WAVE per row: convert 1024 floats -> bf16 (16B stores) + exact fp32 norm.
__global__ void prep_all(const float* __restrict__ feat, const float* __restrict__ cent,
                         u16* __restrict__ Ab, u16* __restrict__ Bb,
                         float* __restrict__ asq, float* __restrict__ bsq) {
  const int lane = threadIdx.x & 63;
  const int row  = (blockIdx.x * blockDim.x + threadIdx.x) >> 6;  // global wave id
  const float* src; u16* dst; float* sq;
  if (row < MROWS) {
    src = feat + (size_t)row * DDIM; dst = Ab + (size_t)row * DDIM; sq = asq + row;
  } else {
    const int r = row - MROWS;
    src = cent + (size_t)r * DDIM;   dst = Bb + (size_t)r * DDIM;  sq = bsq + r;
  }
  float s = 0.f;
  #pragma unroll
  for (int h = 0; h < 2; ++h) {
    const int base = h * 512 + lane * 8;          // 8 consecutive floats per lane
    const float4v v0 = *(const float4v*)(src + base);
    const float4v v1 = *(const float4v*)(src + base + 4);
    ushort8 o;
    o[0] = f32_to_bf16_rne(v0[0]); o[1] = f32_to_bf16_rne(v0[1]);
    o[2] = f32_to_bf16_rne(v0[2]); o[3] = f32_to_bf16_rne(v0[3]);
    o[4] = f32_to_bf16_rne(v1[0]); o[5] = f32_to_bf16_rne(v1[1]);
    o[6] = f32_to_bf16_rne(v1[2]); o[7] = f32_to_bf16_rne(v1[3]);
    *(ushort8*)(dst + base) = o;                  // 16B store
    s += v0[0]*v0[0] + v0[1]*v0[1] + v0[2]*v0[2] + v0[3]*v0[3]
       + v1[0]*v1[0] + v1[1]*v1[1] + v1[2]*v1[2] + v1[3]*v1[3];
  }
  #pragma unroll
  for (int off = 32; off > 0; off >>= 1) s += __shfl_down(s, off, 64);
  if (lane == 0) *sq = s;
}

__device__ __forceinline__ void load_lds16(const u16* g, u16* l) {
  __builtin_amdgcn_global_load_lds(
      (const __attribute__((address_space(1))) u32*)g,
      (__attribute__((address_space(3))) u32*)l, 16, 0, 0);
}

#define MEMFENCE() asm volatile("" ::: "memory")
#define BARRIER() do { MEMFENCE(); __builtin_amdgcn_s_barrier(); MEMFENCE(); } while (0)
#define WAIT_LGKM0() do { asm volatile("s_waitcnt lgkmcnt(0)" ::: "memory"); \
                          __builtin_amdgcn_sched_barrier(0); } while (0)
#define WAIT_VM(N) asm volatile("s_waitcnt vmcnt(" #N ")" ::: "memory")
#define MFMA16(va, vb, vc) __builtin_amdgcn_mfma_f32_16x16x32_bf16((va), (vb), (vc), 0, 0, 0)

// C = A[M,D] * B[K,D]^T, epilogue dist = asq[m] + bsq[n] - 2*C.
//
// 256x256 tile, BK=64, 512 threads = 8 waves (2M x 4N), per-wave output 128x64.
// LDS: per buffer, A and B each split in two 128x64 halves (16 KB each) ->
// 2 buf x 4 halves x 16 KB = 128 KiB. Within a half: row-major 128 rows x 64
// bf16; 16B chunk kc of row r stored at physical chunk kc ^ (r&7) (source
// pre-swizzled so the global_load_lds LDS destination stays lane-contiguous).
// Fragment reads (16 lanes, rows base+l16, fixed logical chunk) spread 2
// lanes/bank = conflict-free.
//
// Per K-tile window of 4 phases (each: [ds_read regs | stage] -> s_barrier ->
// lgkmcnt(0) -> setprio(1) 16xMFMA setprio(0) -> s_barrier):
//   ph1: read a(i0..3, kk0..1) + b(j0..1, kk0..1)        ; mfma (i0..3)x(j0..1)
//   ph2: read b(j2..3)                                   ; mfma (i0..3)x(j2..3)
//   ph3: read a(i4..7)         ; stage B-h0 of tile t+2  ; mfma (i4..7)x(j2..3)
//   ph4: stage B-h1,A-h0,A-h1 of t+2 ; vmcnt(8)          ; mfma (i4..7)x(j0..1)
// Hazards: B(t) last read ph2 -> B(t+2) staged ph3/ph4 is after its drain;
// A(t) last read ph3 -> A(t+2) staged ph4. vmcnt(8) leaves exactly tile t+2's
// 8 loads in flight and guarantees tile t+1 fully landed before its window.
// Tail (t+2 >= NTILES): no stage, vmcnt(0) once.
__global__ __launch_bounds__(512, 2)
void dist_gemm(const u16* __restrict__ A, const u16* __restrict__ B,
               const float* __restrict__ asq, const float* __restrict__ bsq,
               float* __restrict__ out) {
  __shared__ __align__(16) u16 sA[2][2][128 * 64];   // 64 KB
  __shared__ __align__(16) u16 sB[2][2][128 * 64];   // 64 KB

  const int tid  = threadIdx.x;          // 0..511
  const int lane = tid & 63;
  const int quad = lane >> 4;            // 0..3
  const int l16  = lane & 15;
  const int sw   = l16 & 7;              // read-swizzle term (row&7 == l16&7)
  const int wave = tid >> 6;             // 0..7
  const int wm   = wave >> 2;            // 0..1  (M half)
  const int wn   = wave & 3;             // 0..3  (N quarter)

  // XCD-aware remap: each XCD gets 8 row-panels x all 8 col-panels.
  const int bid = blockIdx.x;            // 0..511
  const int xcd = bid & 7;
  const int j   = bid >> 3;              // 0..63
  const int by  = xcd * 8 + (j >> 3);    // row panel 0..63
  const int bx  = j & 7;                 // col panel 0..7 (fastest)
  const int rowBase = by * BM;
  const int colBase = bx * BN;

  // Per-thread staging offsets: 1024 16B-chunks per half, 2 per thread.
  int srcOff[2], ldsOff[2];
  #pragma unroll
  for (int p = 0; p < 2; ++p) {
    const int c  = p * 512 + tid;        // chunk 0..1023
    const int r  = c >> 3;               // row 0..127
    const int kc = (c & 7) ^ (r & 7);    // swizzled global 16B-chunk
    ldsOff[p] = c * 8;                   // u16 units, lane-contiguous
    srcOff[p] = r * DDIM + kc * 8;       // u16 units
  }
  const u16* gA0 = A + (size_t)(rowBase)       * DDIM;
  const u16* gA1 = A + (size_t)(rowBase + 128) * DDIM;
  const u16* gB0 = B + (size_t)(colBase)       * DDIM;
  const u16* gB1 = B + (size_t)(colBase + 128) * DDIM;

  #define STAGE(GBASE, K0, DST) do {                                   \
    load_lds16((GBASE) + srcOff[0] + (K0), (DST) + ldsOff[0]);         \
    load_lds16((GBASE) + srcOff[1] + (K0), (DST) + ldsOff[1]);         \
  } while (0)

  // Fragment read offsets (u16 units): row*64 + (chunk ^ (row&7))*8.
  const int ck0   = (quad ^ sw) * 8;         // kk=0 -> logical chunk quad
  const int ck1   = ((4 + quad) ^ sw) * 8;   // kk=1 -> logical chunk 4+quad
  const int aBase = l16 * 64;
  const int bBase = ((wn & 1) * 64 + l16) * 64;

  float4v acc[8][4];
  #pragma unroll
  for (int i = 0; i < 8; ++i)
    #pragma unroll
    for (int jj = 0; jj < 4; ++jj)
      acc[i][jj] = (float4v)(0.0f);

  // Prologue: tile 0 -> buf0, tile 1 -> buf1; wait tile 0 landed (8 newest
  // = tile 1 may stay in flight).
  STAGE(gB0, 0, &sB[0][0][0]); STAGE(gB1, 0, &sB[0][1][0]);
  STAGE(gA0, 0, &sA[0][0][0]); STAGE(gA1, 0, &sA[0][1][0]);
  STAGE(gB0, BK, &sB[1][0][0]); STAGE(gB1, BK, &sB[1][1][0]);
  STAGE(gA0, BK, &sA[1][0][0]); STAGE(gA1, BK, &sA[1][1][0]);
  WAIT_VM(8);
  BARRIER();

  auto window = [&](int buf, int kt) {
    const u16* pA = &sA[buf][wm][0];
    const u16* pB = &sB[buf][wn >> 1][0];
    const int  st = kt + 2;                 // stage target tile (same parity)
    const bool doStage = (st < NTILES);
    const int  sk = st * BK;
    u16* dA0 = &sA[buf][0][0]; u16* dA1 = &sA[buf][1][0];
    u16* dB0 = &sB[buf][0][0]; u16* dB1 = &sB[buf][1][0];

    short8 a[4][2], b[4][2];

    // ---- phase 1: read a(i0..3), b(j0..1); mfma quadrant (m0, n-lo)
    #pragma unroll
    for (int i = 0; i < 4; ++i) {
      a[i][0] = *(const short8*)&pA[aBase + i * 1024 + ck0];
      a[i][1] = *(const short8*)&pA[aBase + i * 1024 + ck1];
    }
    #pragma unroll
    for (int jj = 0; jj < 2; ++jj) {
      b[jj][0] = *(const short8*)&pB[bBase + jj * 1024 + ck0];
      b[jj][1] = *(const short8*)&pB[bBase + jj * 1024 + ck1];
    }
    BARRIER(); WAIT_LGKM0();
    __builtin_amdgcn_s_setprio(1);
    #pragma unroll
    for (int i = 0; i < 4; ++i)
      #pragma unroll
      for (int jj = 0; jj < 2; ++jj) {
        acc[i][jj] = MFMA16(a[i][0], b[jj][0], acc[i][jj]);
        acc[i][jj] = MFMA16(a[i][1], b[jj][1], acc[i][jj]);
      }
    __builtin_amdgcn_s_setprio(0);
    BARRIER();

    // ---- phase 2: read b(j2..3); mfma quadrant (m0, n-hi)
    #pragma unroll
    for (int jj = 2; jj < 4; ++jj) {
      b[jj][0] = *(const short8*)&pB[bBase + jj * 1024 + ck0];
      b[jj][1] = *(const short8*)&pB[bBase + jj * 1024 + ck1];
    }
    BARRIER(); WAIT_LGKM0();
    __builtin_amdgcn_s_setprio(1);
    #pragma unroll
    for (int i = 0; i < 4; ++i)
      #pragma unroll
      for (int jj = 2; jj < 4; ++jj) {
        acc[i][jj] = MFMA16(a[i][0], b[jj][0], acc[i][jj]);
        acc[i][jj] = MFMA16(a[i][1], b[jj][1], acc[i][jj]);
      }
    __builtin_amdgcn_s_setprio(0);
    BARRIER();

    // ---- phase 3: read a(i4..7); stage B-h0(t+2); mfma quadrant (m1, n-hi)
    #pragma unroll
    for (int i = 0; i < 4; ++i) {
      a[i][0] = *(const short8*)&pA[aBase + (i + 4) * 1024 + ck0];
      a[i][1] = *(const short8*)&pA[aBase + (i + 4) * 1024 + ck1];
    }
    if (doStage) STAGE(gB0, sk, dB0);
    BARRIER(); WAIT_LGKM0();
    __builtin_amdgcn_s_setprio(1);
    #pragma unroll
    for (int i = 0; i < 4; ++i)
      #pragma unroll
      for (int jj = 2; jj < 4; ++jj) {
        acc[i + 4][jj] = MFMA16(a[i][0], b[jj][0], acc[i + 4][jj]);
        acc[i + 4][jj] = MFMA16(a[i][1], b[jj][1], acc[i + 4][jj]);
      }
    __builtin_amdgcn_s_setprio(0);
    BARRIER();

    // ---- phase 4: stage B-h1,A-h0,A-h1(t+2); counted vmcnt; mfma (m1, n-lo)
    if (doStage) {
      STAGE(gB1, sk, dB1); STAGE(gA0, sk, dA0); STAGE(gA1, sk, dA1);
      WAIT_VM(8);           // tile t+1 fully landed; t+2's 8 loads in flight
    } else {
      WAIT_VM(0);           // tail: drain once
    }
    BARRIER();
    __builtin_amdgcn_s_setprio(1);
    #pragma unroll
    for (int i = 0; i < 4; ++i)
      #pragma unroll
      for (int jj = 0; jj < 2; ++jj) {
        acc[i + 4][jj] = MFMA16(a[i][0], b[jj][0], acc[i + 4][jj]);
        acc[i + 4][jj] = MFMA16(a[i][1], b[jj][1], acc[i + 4][jj]);
      }
    __builtin_amdgcn_s_setprio(0);
    BARRIER();
  };

  #pragma unroll 1
  for (int kt = 0; kt < NTILES; kt += 2) {
    window(0, kt);
    window(1, kt + 1);
  }
  #undef STAGE

  // Epilogue. C/D layout: col = lane&15, row = quad*4 + reg (m89/m91).
  #pragma unroll
  for (int i = 0; i < 8; ++i) {
    const int row0 = rowBase + wm * 128 + i * 16 + quad * 4;
    float as4[4];
    #pragma unroll
    for (int r = 0; r < 4; ++r) as4[r] = asq[row0 + r];
    #pragma unroll
    for (int jj = 0; jj < 4; ++jj) {
      const int col = colBase + wn * 64 + jj * 16 + l16;
      const float bs = bsq[col];
      #pragma unroll
      for (int r = 0; r < 4; ++r) {
        out[(size_t)(row0 + r) * NCOLS + col] = as4[r] + bs - 2.0f * acc[i][jj][r];
      }
    }
  }
}

// Safety net only (ws too small): plain fp32, correct but slow.
__global__ void naive_dist(const float* __restrict__ feat, const float* __restrict__ cent,
                           float* __restrict__ out) {
  const int k = blockIdx.x * 16 + threadIdx.x;
  const int n = blockIdx.y * 16 + threadIdx.y;
  const float* fp = feat + (size_t)n * DDIM;
  const float* cp = cent + (size_t)k * DDIM;
  float s = 0.f;
  for (int d = 0; d < DDIM; ++d) { float df = fp[d] - cp[d]; s += df * df; }
  out[(size_t)n * NCOLS + k] = s;
}

extern "C" void kernel_launch(void* const* d_in, const int* in_sizes, int n_in,
                              void* d_out, int out_size, void* d_ws, size_t ws_size,
                              hipStream_t stream) {
  const float* feat    = (const float*)d_in[0];   // [16384, 1024]
  const float* centers = (const float*)d_in[1];   // [2048, 1024]
  float* out = (float*)d_out;                     // [16384, 2048]

  const size_t offA   = 0;
  const size_t offB   = (size_t)MROWS * DDIM * 2;            // 33,554,432
  const size_t offAsq = offB + (size_t)NCOLS * DDIM * 2;     // 37,748,736
  const size_t offBsq = offAsq + (size_t)MROWS * 4;          // 37,814,272
  const size_t need   = offBsq + (size_t)NCOLS * 4;          // ~37.8 MB

  if (ws_size < need) {
    dim3 grid(NCOLS / 16, MROWS / 16), block(16, 16);
    naive_dist<<<grid, block, 0, stream>>>(feat, centers, out);
    return;
  }

  u16*   Ab  = (u16*)((char*)d_ws + offA);
  u16*   Bb  = (u16*)((char*)d_ws + offB);
  float* asq = (float*)((char*)d_ws + offAsq);
  float* bsq = (float*)((char*)d_ws + offBsq);

  prep_all<<<(MROWS + NCOLS) / 4, 256, 0, stream>>>(feat, centers, Ab, Bb, asq, bsq);

  dim3 grid((MROWS / BM) * (NCOLS / BN));   // 512
  dist_gemm<<<grid, 512, 0, stream>>>(Ab, Bb, asq, bsq, out);
}

// Round 3
// 251.598 us; speedup vs baseline: 1.0202x; 1.0202x over previous
//
#include <hip/hip_runtime.h>

// dist[N,K] = ||feat_n||^2 + ||cent_k||^2 - 2 feat . cent
// N=16384, K=2048, D=1024, fp32 in/out.
// bf16 MFMA GEMM, 256x256 tile, BK=64, 8 waves (2Mx4N), 128 KiB double-buffered
// LDS. K-tile flow: register-double-buffered fragments, 2 barriers per K-tile
// (pre-stage hazard + release), counted vmcnt(8), compiler-counted lgkmcnt
// (no per-phase drains), setprio(1) around MFMA clusters, 16B-chunk XOR bank
// swizzle, XCD-aware remap. Prep: one wave per row, bf16 convert + fp32 norms.
// (Resubmission of round-1 kernel: bench infra failed before measuring it.)

#define MROWS 16384
#define NCOLS 2048
#define DDIM  1024
#define BM 256
#define BN 256
#define BK 64
#define NTILES (DDIM / BK)   // 16

typedef unsigned short u16;
typedef unsigned int   u32;
typedef __attribute__((ext_vector_type(8))) short          short8;
typedef __attribute__((ext_vector_type(8))) unsigned short ushort8;
typedef __attribute__((ext_vector_type(4))) float          float4v;

__device__ __forceinline__ u16 f32_to_bf16_rne(float f) {
  u32 u = __float_as_uint(f);
  u32 r = u + 0x7FFFu + ((u >> 16) & 1u);   // round-to-nearest-even
  return (u16)(r >> 16);
}

// One WAVE per row: convert 1024 floats -> bf16 (16B stores) + exact fp32 norm.
__global__ void prep_all(const float* __restrict__ feat, const float* __restrict__ cent,
                         u16* __restrict__ Ab, u16* __restrict__ Bb,
                         float* __restrict__ asq, float* __restrict__ bsq) {
  const int lane = threadIdx.x & 63;
  const int row  = (blockIdx.x * blockDim.x + threadIdx.x) >> 6;  // global wave id
  const float* src; u16* dst; float* sq;
  if (row < MROWS) {
    src = feat + (size_t)row * DDIM; dst = Ab + (size_t)row * DDIM; sq = asq + row;
  } else {
    const int r = row - MROWS;
    src = cent + (size_t)r * DDIM;   dst = Bb + (size_t)r * DDIM;  sq = bsq + r;
  }
  float s = 0.f;
  #pragma unroll
  for (int h = 0; h < 2; ++h) {
    const int base = h * 512 + lane * 8;          // 8 consecutive floats per lane
    const float4v v0 = *(const float4v*)(src + base);
    const float4v v1 = *(const float4v*)(src + base + 4);
    ushort8 o;
    o[0] = f32_to_bf16_rne(v0[0]); o[1] = f32_to_bf16_rne(v0[1]);
    o[2] = f32_to_bf16_rne(v0[2]); o[3] = f32_to_bf16_rne(v0[3]);
    o[4] = f32_to_bf16_rne(v1[0]); o[5] = f32_to_bf16_rne(v1[1]);
    o[6] = f32_to_bf16_rne(v1[2]); o[7] = f32_to_bf16_rne(v1[3]);
    *(ushort8*)(dst + base) = o;                  // 16B store
    s += v0[0]*v0[0] + v0[1]*v0[1] + v0[2]*v0[2] + v0[3]*v0[3]
       + v1[0]*v1[0] + v1[1]*v1[1] + v1[2]*v1[2] + v1[3]*v1[3];
  }
  #pragma unroll
  for (int off = 32; off > 0; off >>= 1) s += __shfl_down(s, off, 64);
  if (lane == 0) *sq = s;
}

__device__ __forceinline__ void load_lds16(const u16* g, u16* l) {
  __builtin_amdgcn_global_load_lds(
      (const __attribute__((address_space(1))) u32*)g,
      (__attribute__((address_space(3))) u32*)l, 16, 0, 0);
}

#define MEMFENCE() asm volatile("" ::: "memory")
#define BARRIER() do { MEMFENCE(); __builtin_amdgcn_s_barrier(); MEMFENCE(); } while (0)
#define WAIT_LGKM0() do { asm volatile("s_waitcnt lgkmcnt(0)" ::: "memory"); \
                          __builtin_amdgcn_sched_barrier(0); } while (0)
#define WAIT_VM(N) asm volatile("s_waitcnt vmcnt(" #N ")" ::: "memory")
#define MFMA16(va, vb, vc) __builtin_amdgcn_mfma_f32_16x16x32_bf16((va), (vb), (vc), 0, 0, 0)

// C = A[M,D] * B[K,D]^T, epilogue dist = asq[m] + bsq[n] - 2*C.
//
// 256x256 tile, BK=64, 512 threads = 8 waves (2M x 4N), per-wave output 128x64.
// LDS: per buffer, A and B each split in two 128x64 halves (16 KB each) ->
// 2 buf x 4 halves x 16 KB = 128 KiB. Within a half: row-major 128 rows x 64
// bf16; 16B chunk kc of row r stored at physical chunk kc ^ (r&7) (source
// pre-swizzled so the global_load_lds LDS destination stays lane-contiguous).
// Fragment reads (16 lanes, rows base+l16, fixed logical chunk) spread 2
// lanes/bank = conflict-free (measured 0 conflicts).
//
// Per K-tile t (buf = t&1), fragments register-double-buffered:
//   [aLo,bLo for tile t already in regs from boundary read of t-1]
//   issue ds_reads bHi, aHi (12 x b128)          <- latency hides under Qa
//   MFMA Qa (aLo x bLo -> acc[0..3][0..1])        no explicit lgkm wait:
//   MFMA Qb (aLo x bHi -> acc[0..3][2..3])        compiler counts exactly
//   lgkmcnt(0); s_barrier                         <- all waves' reads of buf done
//   stage tile t+2 -> buf (8 global_load_lds)     <- write-after-read safe
//   MFMA Qc (aHi x bHi -> acc[4..7][2..3])        pure-register, hides stage
//   MFMA Qd (aHi x bLo -> acc[4..7][0..1])
//   vmcnt(8); s_barrier                           <- tile t+1 landed, publish
//   boundary read aLo,bLo of tile t+1 from buf^1
// 2 barriers + 1 (covered) lgkm drain per K-tile, vs 8 + 4 in the lockstep
// phase version that measured MfmaUtil 31%.
__global__ __launch_bounds__(512, 2)
void dist_gemm(const u16* __restrict__ A, const u16* __restrict__ B,
               const float* __restrict__ asq, const float* __restrict__ bsq,
               float* __restrict__ out) {
  __shared__ __align__(16) u16 sA[2][2][128 * 64];   // 64 KB
  __shared__ __align__(16) u16 sB[2][2][128 * 64];   // 64 KB

  const int tid  = threadIdx.x;          // 0..511
  const int lane = tid & 63;
  const int quad = lane >> 4;            // 0..3
  const int l16  = lane & 15;
  const int sw   = l16 & 7;              // read-swizzle term (row&7 == l16&7)
  const int wave = tid >> 6;             // 0..7
  const int wm   = wave >> 2;            // 0..1  (M half)
  const int wn   = wave & 3;             // 0..3  (N quarter)

  // XCD-aware remap: each XCD gets 8 row-panels x all 8 col-panels.
  const int bid = blockIdx.x;            // 0..511
  const int xcd = bid & 7;
  const int j   = bid >> 3;              // 0..63
  const int by  = xcd * 8 + (j >> 3);    // row panel 0..63
  const int bx  = j & 7;                 // col panel 0..7 (fastest)
  const int rowBase = by * BM;
  const int colBase = bx * BN;

  // Per-thread staging offsets: 1024 16B-chunks per half, 2 per thread.
  int srcOff[2], ldsOff[2];
  #pragma unroll
  for (int p = 0; p < 2; ++p) {
    const int c  = p * 512 + tid;        // chunk 0..1023
    const int r  = c >> 3;               // row 0..127
    const int kc = (c & 7) ^ (r & 7);    // swizzled global 16B-chunk
    ldsOff[p] = c * 8;                   // u16 units, lane-contiguous
    srcOff[p] = r * DDIM + kc * 8;       // u16 units
  }
  const u16* gA0 = A + (size_t)(rowBase)       * DDIM;
  const u16* gA1 = A + (size_t)(rowBase + 128) * DDIM;
  const u16* gB0 = B + (size_t)(colBase)       * DDIM;
  const u16* gB1 = B + (size_t)(colBase + 128) * DDIM;

  #define STAGE(GBASE, K0, DST) do {                                   \
    load_lds16((GBASE) + srcOff[0] + (K0), (DST) + ldsOff[0]);         \
    load_lds16((GBASE) + srcOff[1] + (K0), (DST) + ldsOff[1]);         \
  } while (0)

  // Fragment read offsets (u16 units): row*64 + (chunk ^ (row&7))*8.
  const int ck0   = (quad ^ sw) * 8;         // kk=0 -> logical chunk quad
  const int ck1   = ((4 + quad) ^ sw) * 8;   // kk=1 -> logical chunk 4+quad
  const int aBase = l16 * 64;
  const int bBase = ((wn & 1) * 64 + l16) * 64;

  float4v acc[8][4];
  #pragma unroll
  for (int i = 0; i < 8; ++i)
    #pragma unroll
    for (int jj = 0; jj < 4; ++jj)
      acc[i][jj] = (float4v)(0.0f);

  // Prologue: tile 0 -> buf0, tile 1 -> buf1; wait tile 0 landed (8 newest
  // = tile 1 may stay in flight).
  STAGE(gB0, 0, &sB[0][0][0]); STAGE(gB1, 0, &sB[0][1][0]);
  STAGE(gA0, 0, &sA[0][0][0]); STAGE(gA1, 0, &sA[0][1][0]);
  STAGE(gB0, BK, &sB[1][0][0]); STAGE(gB1, BK, &sB[1][1][0]);
  STAGE(gA0, BK, &sA[1][0][0]); STAGE(gA1, BK, &sA[1][1][0]);
  WAIT_VM(8);
  BARRIER();

  short8 aLo[4][2], bLo[2][2], aHi[4][2], bHi[2][2];
  {
    const u16* pA = &sA[0][wm][0];
    const u16* pB = &sB[0][wn >> 1][0];
    #pragma unroll
    for (int i = 0; i < 4; ++i) {
      aLo[i][0] = *(const short8*)&pA[aBase + i * 1024 + ck0];
      aLo[i][1] = *(const short8*)&pA[aBase + i * 1024 + ck1];
    }
    #pragma unroll
    for (int jj = 0; jj < 2; ++jj) {
      bLo[jj][0] = *(const short8*)&pB[bBase + jj * 1024 + ck0];
      bLo[jj][1] = *(const short8*)&pB[bBase + jj * 1024 + ck1];
    }
  }

  #pragma unroll 1
  for (int kt = 0; kt < NTILES; ++kt) {
    const int  buf = kt & 1;
    const u16* pA  = &sA[buf][wm][0];
    const u16* pB  = &sB[buf][wn >> 1][0];
    const int  st  = kt + 2;
    const bool doStage = (st < NTILES);
    const int  sk  = st * BK;
    u16* dA0 = &sA[buf][0][0]; u16* dA1 = &sA[buf][1][0];
    u16* dB0 = &sB[buf][0][0]; u16* dB1 = &sB[buf][1][0];

    // Issue the rest of this tile's fragment reads (latency hides under Qa).
    #pragma unroll
    for (int jj = 0; jj < 2; ++jj) {
      bHi[jj][0] = *(const short8*)&pB[bBase + (jj + 2) * 1024 + ck0];
      bHi[jj][1] = *(const short8*)&pB[bBase + (jj + 2) * 1024 + ck1];
    }
    #pragma unroll
    for (int i = 0; i < 4; ++i) {
      aHi[i][0] = *(const short8*)&pA[aBase + (i + 4) * 1024 + ck0];
      aHi[i][1] = *(const short8*)&pA[aBase + (i + 4) * 1024 + ck1];
    }

    // Qa (aLo x bLo) + Qb (aLo x bHi): compiler inserts counted lgkmcnt.
    __builtin_amdgcn_s_setprio(1);
    #pragma unroll
    for (int i = 0; i < 4; ++i)
      #pragma unroll
      for (int jj = 0; jj < 2; ++jj) {
        acc[i][jj] = MFMA16(aLo[i][0], bLo[jj][0], acc[i][jj]);
        acc[i][jj] = MFMA16(aLo[i][1], bLo[jj][1], acc[i][jj]);
      }
    #pragma unroll
    for (int i = 0; i < 4; ++i)
      #pragma unroll
      for (int jj = 0; jj < 2; ++jj) {
        acc[i][jj + 2] = MFMA16(aLo[i][0], bHi[jj][0], acc[i][jj + 2]);
        acc[i][jj + 2] = MFMA16(aLo[i][1], bHi[jj][1], acc[i][jj + 2]);
      }
    __builtin_amdgcn_s_setprio(0);

    // All of this wave's reads of buf are complete -> rendezvous -> safe to
    // overwrite buf with tile t+2.
    WAIT_LGKM0();
    BARRIER();
    if (doStage) {
      STAGE(gB0, sk, dB0); STAGE(gB1, sk, dB1);
      STAGE(gA0, sk, dA0); STAGE(gA1, sk, dA1);
    }

    // Qc (aHi x bHi) + Qd (aHi x bLo): pure-register, hides staging issue.
    __builtin_amdgcn_s_setprio(1);
    #pragma unroll
    for (int i = 0; i < 4; ++i)
      #pragma unroll
      for (int jj = 0; jj < 2; ++jj) {
        acc[i + 4][jj + 2] = MFMA16(aHi[i][0], bHi[jj][0], acc[i + 4][jj + 2]);
        acc[i + 4][jj + 2] = MFMA16(aHi[i][1], bHi[jj][1], acc[i + 4][jj + 2]);
      }
    #pragma unroll
    for (int i = 0; i < 4; ++i)
      #pragma unroll
      for (int jj = 0; jj < 2; ++jj) {
        acc[i + 4][jj] = MFMA16(aHi[i][0], bLo[jj][0], acc[i + 4][jj]);
        acc[i + 4][jj] = MFMA16(aHi[i][1], bLo[jj][1], acc[i + 4][jj]);
      }
    __builtin_amdgcn_s_setprio(0);

    // Release: tile t+1 (staged one K-tile ago) fully landed; t+2's 8 loads
    // stay in flight. Tail drains to 0.
    if (doStage) { WAIT_VM(8); } else { WAIT_VM(0); }
    BARRIER();

    // Boundary read: next tile's Qa fragments from the other buffer.
    if (kt + 1 < NTILES) {
      const int  nb = buf ^ 1;
      const u16* qA = &sA[nb][wm][0];
      const u16* qB = &sB[nb][wn >> 1][0];
      #pragma unroll
      for (int i = 0; i < 4; ++i) {
        aLo[i][0] = *(const short8*)&qA[aBase + i * 1024 + ck0];
        aLo[i][1] = *(const short8*)&qA[aBase + i * 1024 + ck1];
      }
      #pragma unroll
      for (int jj = 0; jj < 2; ++jj) {
        bLo[jj][0] = *(const short8*)&qB[bBase + jj * 1024 + ck0];
        bLo[jj][1] = *(const short8*)&qB[bBase + jj * 1024 + ck1];
      }
    }
  }
  #undef STAGE

  // Epilogue. C/D layout: col = lane&15, row = quad*4 + reg (m89/m91).
  #pragma unroll
  for (int i = 0; i < 8; ++i) {
    const int row0 = rowBase + wm * 128 + i * 16 + quad * 4;
    float as4[4];
    #pragma unroll
    for (int r = 0; r < 4; ++r) as4[r] = asq[row0 + r];
    #pragma unroll
    for (int jj = 0; jj < 4; ++jj) {
      const int col = colBase + wn * 64 + jj * 16 + l16;
      const float bs = bsq[col];
      #pragma unroll
      for (int r = 0; r < 4; ++r) {
        out[(size_t)(row0 + r) * NCOLS + col] = as4[r] + bs - 2.0f * acc[i][jj][r];
      }
    }
  }
}

// Safety net only (ws too small): plain fp32, correct but slow.
__global__ void naive_dist(const float* __restrict__ feat, const float* __restrict__ cent,
                           float* __restrict__ out) {
  const int k = blockIdx.x * 16 + threadIdx.x;
  const int n = blockIdx.y * 16 + threadIdx.y;
  const float* fp = feat + (size_t)n * DDIM;
  const float* cp = cent + (size_t)k * DDIM;
  float s = 0.f;
  for (int d = 0; d < DDIM; ++d) { float df = fp[d] - cp[d]; s += df * df; }
  out[(size_t)n * NCOLS + k] = s;
}

extern "C" void kernel_launch(void* const* d_in, const int* in_sizes, int n_in,
                              void* d_out, int out_size, void* d_ws, size_t ws_size,
                              hipStream_t stream) {
  const float* feat    = (const float*)d_in[0];   // [16384, 1024]
  const float* centers = (const float*)d_in[1];   // [2048, 1024]
  float* out = (float*)d_out;                     // [16384, 2048]

  const size_t offA   = 0;
  const size_t offB   = (size_t)MROWS * DDIM * 2;            // 33,554,432
  const size_t offAsq = offB + (size_t)NCOLS * DDIM * 2;     // 37,748,736
  const size_t offBsq = offAsq + (size_t)MROWS * 4;          // 37,814,272
  const size_t need   = offBsq + (size_t)NCOLS * 4;          // ~37.8 MB

  if (ws_size < need) {
    dim3 grid(NCOLS / 16, MROWS / 16), block(16, 16);
    naive_dist<<<grid, block, 0, stream>>>(feat, centers, out);
    return;
  }

  u16*   Ab  = (u16*)((char*)d_ws + offA);
  u16*   Bb  = (u16*)((char*)d_ws + offB);
  float* asq = (float*)((char*)d_ws + offAsq);
  float* bsq = (float*)((char*)d_ws + offBsq);

  prep_all<<<(MROWS + NCOLS) / 4, 256, 0, stream>>>(feat, centers, Ab, Bb, asq, bsq);

  dim3 grid((MROWS / BM) * (NCOLS / BN));   // 512
  dist_gemm<<<grid, 512, 0, stream>>>(Ab, Bb, asq, bsq, out);
}